// Round 4
// baseline (79.647 us; speedup 1.0000x reference)
//
#include <hip/hip_runtime.h>

// LengthRegulator fused: x (B=32, C=384, T=1024) f32, duration (B,T) i32 in [0,8),
// max_len = 7168. One kernel: each block = (batch b, 1024-frame tile, 32 channels).
// Block re-computes duration scan (4KB + shuffle scan), early-exits to pure zero
// stores when the whole tile is past mel_len, else scatters the tile's
// frame->token map into LDS and gathers 32 channels with token ids in registers.
// out0 = gathered x (zero past mel_len); out1 = mel_len as f32.

#define B_ 32
#define C_ 384
#define T_ 1024
#define MAXLEN_ 7168
#define FT_ 7          // frame tiles of 1024 (7*1024 = 7168)
#define CPB_ 32        // channels per block (amortize scan/scatter prologue)
#define NT_ 256        // threads per block

typedef float f32x4 __attribute__((ext_vector_type(4)));

__global__ __launch_bounds__(NT_) void lr_fused_kernel(
    const int* __restrict__ dur,     // (B, T)
    const float* __restrict__ x,     // (B, C, T)
    float* __restrict__ out,         // (B, C, MAXLEN)
    float* __restrict__ mel_out)     // (B,) stored as float
{
    const int tid   = threadIdx.x;
    const int ftile = blockIdx.x;    // 0..FT_-1
    const int cblk  = blockIdx.y;    // 0..C_/CPB_-1
    const int b     = blockIdx.z;    // 0..B_-1
    const int f0    = ftile << 10;   // tile start frame

    __shared__ int s_tok[1024];      // frame->token map for this tile
    __shared__ int s_w[NT_ / 64];    // per-wave scan totals

    // ---- each thread loads 4 consecutive durations (coalesced int4) ----
    const int4 d4 = ((const int4*)(dur + b * T_))[tid];
    const int sum4 = d4.x + d4.y + d4.z + d4.w;

    // ---- inclusive scan of per-thread sums: wave shuffle + LDS cross-wave ----
    const int lane = tid & 63;
    const int wave = tid >> 6;
    int sc = sum4;
    #pragma unroll
    for (int d = 1; d < 64; d <<= 1) {
        int n = __shfl_up(sc, d, 64);
        if (lane >= d) sc += n;
    }
    if (lane == 63) s_w[wave] = sc;
    __syncthreads();

    int woff = 0;
    #pragma unroll
    for (int w = 0; w < NT_ / 64; ++w)
        woff += (w < wave) ? s_w[w] : 0;
    const int mel = s_w[0] + s_w[1] + s_w[2] + s_w[3];

    if (ftile == 0 && cblk == 0 && tid == 0)
        mel_out[b] = (float)mel;

    float* ob = out + ((size_t)b * C_ + cblk * CPB_) * MAXLEN_ + f0 + (tid << 2);

    // ---- block-uniform fast path: whole tile past mel_len -> zeros only ----
    if (f0 >= mel) {
        const f32x4 z = {0.0f, 0.0f, 0.0f, 0.0f};
        #pragma unroll 8
        for (int cc = 0; cc < CPB_; ++cc)
            __builtin_nontemporal_store(z, (f32x4*)(ob + (size_t)cc * MAXLEN_));
        return;
    }

    // init frame->token map to -1 (frames past mel_len stay -1 -> zero output)
    ((int4*)s_tok)[tid] = make_int4(-1, -1, -1, -1);
    __syncthreads();

    // exclusive start frame of this thread's first token
    const int st = woff + sc - sum4;

    // ---- scatter: token k covers frames [start_k, start_k + dur_k) ----
    {
        const int base_tok = tid << 2;
        const int s0 = st;
        const int s1 = s0 + d4.x;
        const int s2 = s1 + d4.y;
        const int s3 = s2 + d4.z;
        const int starts[4] = { s0, s1, s2, s3 };
        const int lens[4]   = { d4.x, d4.y, d4.z, d4.w };
        #pragma unroll
        for (int k = 0; k < 4; ++k) {
            int lo = starts[k] - f0;
            int hi = lo + lens[k];
            lo = lo < 0 ? 0 : lo;
            hi = hi > 1024 ? 1024 : hi;
            for (int p = lo; p < hi; ++p)
                s_tok[p] = base_tok + k;
        }
    }
    __syncthreads();

    // ---- gather 32 channels; token ids for this thread's 4 frames in regs ----
    const int4 t4 = ((const int4*)s_tok)[tid];

    const float* xb = x + ((size_t)b * C_ + cblk * CPB_) * T_;

    #pragma unroll 4
    for (int cc = 0; cc < CPB_; ++cc) {
        const float* __restrict__ xr = xb + cc * T_;   // 4 KB row
        f32x4 v;
        v.x = (t4.x >= 0) ? xr[t4.x] : 0.0f;
        v.y = (t4.y >= 0) ? xr[t4.y] : 0.0f;
        v.z = (t4.z >= 0) ? xr[t4.z] : 0.0f;
        v.w = (t4.w >= 0) ? xr[t4.w] : 0.0f;
        __builtin_nontemporal_store(v, (f32x4*)(ob + (size_t)cc * MAXLEN_));
    }
}

extern "C" void kernel_launch(void* const* d_in, const int* in_sizes, int n_in,
                              void* d_out, int out_size, void* d_ws, size_t ws_size,
                              hipStream_t stream) {
    const float* x   = (const float*)d_in[0];
    const int*   dur = (const int*)d_in[1];
    // d_in[2] = max_len scalar (7168), compile-time constant here.

    float* out = (float*)d_out;
    float* mel_out = out + (size_t)B_ * C_ * MAXLEN_;  // 32 floats at the tail

    dim3 grid(FT_, C_ / CPB_, B_);
    lr_fused_kernel<<<grid, NT_, 0, stream>>>(dur, x, out, mel_out);
}

// Round 5
// 72.608 us; speedup vs baseline: 1.0969x; 1.0969x over previous
//
#include <hip/hip_runtime.h>

// LengthRegulator fused: x (B=32, C=384, T=1024) f32, duration (B,T) i32 in [0,8),
// max_len = 7168. One kernel; block = (batch b, 1024-frame tile, 8 channels).
// 1D grid with XCD-chunked swizzle so the 7 frame-tiles sharing one x slab
// (and the 336 blocks sharing one dur row) land on the SAME XCD's L2.
// Block re-computes duration scan (4KB + shuffle scan), early-exits to zero
// stores when the tile is past mel_len, else scatters frame->token map into
// LDS and gathers 8 channels. out0 = gathered x; out1 = mel_len as f32.

#define B_ 32
#define C_ 384
#define T_ 1024
#define MAXLEN_ 7168
#define FT_ 7          // frame tiles of 1024 (7*1024 = 7168)
#define CPB_ 8         // channels per block (32 KB x slab = L1-resident)
#define NT_ 256        // threads per block
#define NWG_ (B_ * (C_ / CPB_) * FT_)   // 10752, divisible by 8
#define NXCD_ 8

typedef float f32x4 __attribute__((ext_vector_type(4)));

__global__ __launch_bounds__(NT_) void lr_fused_kernel(
    const int* __restrict__ dur,     // (B, T)
    const float* __restrict__ x,     // (B, C, T)
    float* __restrict__ out,         // (B, C, MAXLEN)
    float* __restrict__ mel_out)     // (B,) stored as float
{
    const int tid = threadIdx.x;

    // ---- XCD-chunked bijective swizzle (T1): consecutive wgid -> same XCD ----
    const int bid  = blockIdx.x;             // HW dispatch round-robins bid%8
    const int wgid = (bid & (NXCD_ - 1)) * (NWG_ / NXCD_) + (bid >> 3);
    const int ftile = wgid % FT_;
    const int rest  = wgid / FT_;
    const int cblk  = rest % (C_ / CPB_);
    const int b     = rest / (C_ / CPB_);
    const int f0    = ftile << 10;           // tile start frame

    __shared__ int s_tok[1024];              // frame->token map for this tile
    __shared__ int s_w[NT_ / 64];            // per-wave scan totals

    // ---- each thread loads 4 consecutive durations (coalesced int4) ----
    const int4 d4 = ((const int4*)(dur + b * T_))[tid];
    const int sum4 = d4.x + d4.y + d4.z + d4.w;

    // ---- inclusive scan of per-thread sums: wave shuffle + LDS cross-wave ----
    const int lane = tid & 63;
    const int wave = tid >> 6;
    int sc = sum4;
    #pragma unroll
    for (int d = 1; d < 64; d <<= 1) {
        int n = __shfl_up(sc, d, 64);
        if (lane >= d) sc += n;
    }
    if (lane == 63) s_w[wave] = sc;
    __syncthreads();

    int woff = 0;
    #pragma unroll
    for (int w = 0; w < NT_ / 64; ++w)
        woff += (w < wave) ? s_w[w] : 0;
    const int mel = s_w[0] + s_w[1] + s_w[2] + s_w[3];

    if (ftile == 0 && cblk == 0 && tid == 0)
        mel_out[b] = (float)mel;

    float* ob = out + ((size_t)b * C_ + cblk * CPB_) * MAXLEN_ + f0 + (tid << 2);

    // ---- block-uniform fast path: whole tile past mel_len -> zeros only ----
    if (f0 >= mel) {
        const f32x4 z = {0.0f, 0.0f, 0.0f, 0.0f};
        #pragma unroll
        for (int cc = 0; cc < CPB_; ++cc)
            __builtin_nontemporal_store(z, (f32x4*)(ob + (size_t)cc * MAXLEN_));
        return;
    }

    // init frame->token map to -1 (frames past mel_len stay -1 -> zero output)
    ((int4*)s_tok)[tid] = make_int4(-1, -1, -1, -1);
    __syncthreads();

    // exclusive start frame of this thread's first token
    const int st = woff + sc - sum4;

    // ---- scatter: token k covers frames [start_k, start_k + dur_k) ----
    {
        const int base_tok = tid << 2;
        const int s0 = st;
        const int s1 = s0 + d4.x;
        const int s2 = s1 + d4.y;
        const int s3 = s2 + d4.z;
        const int starts[4] = { s0, s1, s2, s3 };
        const int lens[4]   = { d4.x, d4.y, d4.z, d4.w };
        #pragma unroll
        for (int k = 0; k < 4; ++k) {
            int lo = starts[k] - f0;
            int hi = lo + lens[k];
            lo = lo < 0 ? 0 : lo;
            hi = hi > 1024 ? 1024 : hi;
            for (int p = lo; p < hi; ++p)
                s_tok[p] = base_tok + k;
        }
    }
    __syncthreads();

    // ---- gather 8 channels; token ids for this thread's 4 frames in regs ----
    const int4 t4 = ((const int4*)s_tok)[tid];

    const float* xb = x + ((size_t)b * C_ + cblk * CPB_) * T_;

    #pragma unroll
    for (int cc = 0; cc < CPB_; ++cc) {
        const float* __restrict__ xr = xb + cc * T_;   // 4 KB row, L1-resident
        f32x4 v;
        v.x = (t4.x >= 0) ? xr[t4.x] : 0.0f;
        v.y = (t4.y >= 0) ? xr[t4.y] : 0.0f;
        v.z = (t4.z >= 0) ? xr[t4.z] : 0.0f;
        v.w = (t4.w >= 0) ? xr[t4.w] : 0.0f;
        __builtin_nontemporal_store(v, (f32x4*)(ob + (size_t)cc * MAXLEN_));
    }
}

extern "C" void kernel_launch(void* const* d_in, const int* in_sizes, int n_in,
                              void* d_out, int out_size, void* d_ws, size_t ws_size,
                              hipStream_t stream) {
    const float* x   = (const float*)d_in[0];
    const int*   dur = (const int*)d_in[1];
    // d_in[2] = max_len scalar (7168), compile-time constant here.

    float* out = (float*)d_out;
    float* mel_out = out + (size_t)B_ * C_ * MAXLEN_;  // 32 floats at the tail

    lr_fused_kernel<<<NWG_, NT_, 0, stream>>>(dur, x, out, mel_out);
}